// Round 8
// baseline (246.695 us; speedup 1.0000x reference)
//
#include <hip/hip_runtime.h>
#include <math.h>

#define B_   128
#define L_   128
#define E_   300
#define P_   50
#define FN_  256
#define H2_  100
#define LAB_ 19

typedef unsigned short ushort_t;
typedef __attribute__((ext_vector_type(8))) short bf16x8;
typedef __attribute__((ext_vector_type(4))) short bf16x4;
typedef __attribute__((ext_vector_type(4))) short short4v;
typedef __attribute__((ext_vector_type(4))) float f32x4;

// folded-K geometry: word K=(k+2)*300 pad64, pos K=k*100 pad64, corr K=960
#define KW0 1536
#define KW1 1856
#define KW2 2112
#define KP0 320
#define KP1 448
#define KP2 512
#define KC  960

#define WE_STRIDE  40960   // per-b we_flat elems (130x300 + zero tail)
#define POS_STRIDE 13312   // per-b posflat elems (128x100 + zero tail)

#define N_WE   (B_ * WE_STRIDE)
#define N_POS  (B_ * POS_STRIDE)
#define N_WFW  (FN_ * (KW0 + KW1 + KW2))
#define N_WFP  (FN_ * (KP0 + KP1 + KP2))
#define N_CORR (3 * FN_ * KC)

#define WEB  (B_ * 35)
#define POSB (B_ * 17)
#define WFWB (N_WFW / 2048)
#define WFPB (N_WFP / 2048)
#define CORB (N_CORR / 2048)
#define SETUP_BLOCKS (WEB + POSB + WFWB + WFPB + CORB)

__device__ __forceinline__ ushort_t f2bf(float x) {
    unsigned u = __float_as_uint(x);
    u += 0x7FFFu + ((u >> 16) & 1u);
    return (ushort_t)(u >> 16);
}
__device__ __forceinline__ float bf2f(ushort_t u) {
    return __uint_as_float((unsigned)u << 16);
}

__device__ __forceinline__ void gld_lds16(const void* g, void* lds_uniform) {
    __builtin_amdgcn_global_load_lds(
        (const __attribute__((address_space(1))) void*)g,
        (__attribute__((address_space(3))) void*)lds_uniform,
        16, 0, 0);
}

__device__ __forceinline__ bf16x8 lds_ld8(const ushort_t* p) {
    bf16x4 lo = *(const bf16x4*)p;
    bf16x4 hi = *(const bf16x4*)(p + 4);
    return __builtin_shufflevector(lo, hi, 0, 1, 2, 3, 4, 5, 6, 7);
}

#define MEMFENCE asm volatile("" ::: "memory")
#define BAR      do { MEMFENCE; __builtin_amdgcn_s_barrier(); MEMFENCE; } while (0)
#define WAITV4   asm volatile("s_waitcnt vmcnt(4)" ::: "memory")
#define WAITV0   asm volatile("s_waitcnt vmcnt(0)" ::: "memory")

// ================= setup: vectorized x8 builds of all staging arrays =========
__global__ __launch_bounds__(256) void setup_kernel(
    const int* __restrict__ inputs, const int* __restrict__ p1, const int* __restrict__ p2,
    const float* __restrict__ emb, const float* __restrict__ pos1, const float* __restrict__ pos2,
    const float* __restrict__ w3, const float* __restrict__ w4, const float* __restrict__ w5,
    ushort_t* __restrict__ we_flat, ushort_t* __restrict__ posflat,
    ushort_t* __restrict__ wfw, ushort_t* __restrict__ wfp, ushort_t* __restrict__ corrw)
{
    int bid = blockIdx.x, t = threadIdx.x;

    if (bid < WEB) {                                  // ---- we_flat
        int b = bid / 35, rb = bid - b * 35;
        int r = rb * 4 + (t >> 6), c8 = t & 63;
        if (c8 >= 38) return;
        int e0 = c8 * 8;
        int n = (e0 + 8 <= 300) ? 8 : 300 - e0;       // 4 at c8=37
        int flat = r * 300 + e0;
        ushort_t* dst = we_flat + (size_t)b * WE_STRIDE + flat;
        if (r < 130) {
            int tok = (r == 0 || r == 129) ? 0 : inputs[b * L_ + r - 1];
            const float* er = emb + (size_t)tok * 300 + e0;
            short4v v0, v1;
#pragma unroll
            for (int m = 0; m < 4; ++m) v0[m] = (short)f2bf(er[m]);
            *(short4v*)dst = v0;
            if (n == 8) {
#pragma unroll
                for (int m = 0; m < 4; ++m) v1[m] = (short)f2bf(er[4 + m]);
                *(short4v*)(dst + 4) = v1;
            }
        } else {                                      // zero tail rows
            short4v z = {0, 0, 0, 0};
            if (flat + 4 <= WE_STRIDE) *(short4v*)dst = z;
            if (n == 8 && flat + 8 <= WE_STRIDE) *(short4v*)(dst + 4) = z;
        }
        return;
    }
    bid -= WEB;
    if (bid < POSB) {                                 // ---- posflat
        int b = bid / 17, rb = bid - b * 17;
        int r = rb * 8 + (t >> 5), c = t & 31;
        if (c >= 25) return;
        int e0 = c * 4;
        int flat = r * 100 + e0;
        ushort_t* dst = posflat + (size_t)b * POS_STRIDE + flat;
        short4v v;
        if (r < 128) {
            int pp1 = p1[b * L_ + r], pp2 = p2[b * L_ + r];
#pragma unroll
            for (int m = 0; m < 4; ++m) {
                int d = e0 + m;
                float x = (d < 50) ? pos1[(size_t)pp1 * 50 + d]
                                   : pos2[(size_t)pp2 * 50 + (d - 50)];
                v[m] = (short)f2bf(x);
            }
            *(short4v*)dst = v;
        } else {
            short4v z = {0, 0, 0, 0};
            if (flat + 4 <= POS_STRIDE) *(short4v*)dst = z;
        }
        return;
    }
    bid -= POSB;
    if (bid < WFWB) {                                 // ---- folded word weights
        int e = (bid * 256 + t) * 8;
        int conv, k, kwp;
        const float* w;
        int seg = e;
        if (seg < FN_ * KW0)                { conv = 0; k = 3; kwp = KW0; w = w3; }
        else if ((seg -= FN_ * KW0) < FN_ * KW1) { conv = 1; k = 4; kwp = KW1; w = w4; }
        else                                { seg -= FN_ * KW1; conv = 2; k = 5; kwp = KW2; w = w5; }
        int f, kk0;
        if (conv == 0) { f = seg / KW0; kk0 = seg - f * KW0; }
        else if (conv == 1) { f = seg / KW1; kk0 = seg - f * KW1; }
        else { f = seg / KW2; kk0 = seg - f * KW2; }
        bf16x8 v;
#pragma unroll
        for (int m = 0; m < 8; ++m) {
            int kk = kk0 + m;
            float s = 0.f;
            if (kk < (k + 2) * 300) {
                int mr = kk / 300, c = kk - mr * 300;
                int jlo = (mr - 2 < 0) ? 0 : mr - 2;
                int jhi = (mr < k - 1) ? mr : k - 1;
                for (int j = jlo; j <= jhi; ++j)
                    s += w[(size_t)f * (k * 1000) + j * 1000 + (mr - j) * 300 + c];
            }
            v[m] = (short)f2bf(s);
        }
        *(bf16x8*)(wfw + e) = v;
        return;
    }
    bid -= WFWB;
    if (bid < WFPB) {                                 // ---- pos weights
        int e = (bid * 256 + t) * 8;
        int conv, k, kpp;
        const float* w;
        int seg = e;
        if (seg < FN_ * KP0)                { conv = 0; k = 3; kpp = KP0; w = w3; }
        else if ((seg -= FN_ * KP0) < FN_ * KP1) { conv = 1; k = 4; kpp = KP1; w = w4; }
        else                                { seg -= FN_ * KP1; conv = 2; k = 5; kpp = KP2; w = w5; }
        int f, kk0;
        if (conv == 0) { f = seg / KP0; kk0 = seg - f * KP0; }
        else if (conv == 1) { f = seg / KP1; kk0 = seg - f * KP1; }
        else { f = seg / KP2; kk0 = seg - f * KP2; }
        bf16x8 v;
#pragma unroll
        for (int m = 0; m < 8; ++m) {
            int kk = kk0 + m;
            float x = 0.f;
            if (kk < k * 100) {
                int j = kk / 100, c = kk - j * 100;
                x = w[(size_t)f * (k * 1000) + j * 1000 + 900 + c];
            }
            v[m] = (short)f2bf(x);
        }
        *(bf16x8*)(wfp + e) = v;
        return;
    }
    bid -= WFPB;
    {                                                 // ---- corr weights w[f,0,0:900]
        int e = (bid * 256 + t) * 8;
        int conv = e / (FN_ * KC), seg = e - conv * (FN_ * KC);
        int k = 3 + conv;
        const float* w = (conv == 0) ? w3 : (conv == 1) ? w4 : w5;
        int f = seg / KC, kk0 = seg - f * KC;
        bf16x8 v;
#pragma unroll
        for (int m = 0; m < 8; ++m) {
            int kk = kk0 + m;
            v[m] = (kk < 900) ? (short)f2bf(w[(size_t)f * (k * 1000) + kk]) : (short)0;
        }
        *(bf16x8*)(corrw + e) = v;
    }
}

// ============ conv: grid (b, 6 tiles of 128 filters); A resident in LDS ======
// 4 waves 2m x 2n, wave tile 64x64 (4mf x 4nf) -> 0.5 KB LDS per MFMA.
// Per-tile K-skip; corr on VALU overlapped with A load; B dbuf swizzled.
__global__ __launch_bounds__(256, 1) void conv_fold(
    const ushort_t* __restrict__ we_flat, const ushort_t* __restrict__ posflat,
    const ushort_t* __restrict__ wfw, const ushort_t* __restrict__ wfp,
    const ushort_t* __restrict__ corrw,
    const float* __restrict__ cb3, const float* __restrict__ cb4, const float* __restrict__ cb5,
    float* __restrict__ sf)
{
    __shared__ ushort_t we_lds[WE_STRIDE];    // 81920 B
    __shared__ ushort_t pos_lds[POS_STRIDE];  // 26624 B
    __shared__ ushort_t sB[2][8192];          // 2 x 16 KB (chunk-swizzled)
    __shared__ float corr_lds[128];
    __shared__ float red[2][128];

    int b = blockIdx.x;
    int y = blockIdx.y;                       // 0..5
    int conv = y >> 1;
    int n0c = (y & 1) << 7;                   // filter offset within conv

    const int ntw = (conv == 0) ? KW0 / 64 : (conv == 1) ? KW1 / 64 : KW2 / 64;
    const int ntp = (conv == 0) ? KP0 / 64 : (conv == 1) ? KP1 / 64 : KP2 / 64;
    const int nt  = ntw + ntp;
    const size_t kwB = (size_t)(ntw * 64) * 2;     // word B row stride bytes
    const size_t kpB = (size_t)(ntp * 64) * 2;
    const size_t wfwoff = (conv == 0) ? 0 : (conv == 1) ? (size_t)FN_ * KW0 : (size_t)FN_ * (KW0 + KW1);
    const size_t wfpoff = (conv == 0) ? 0 : (conv == 1) ? (size_t)FN_ * KP0 : (size_t)FN_ * (KP0 + KP1);
    const char* Bw = (const char*)(wfw + wfwoff + (size_t)n0c * (ntw * 64));
    const char* Bp = (const char*)(wfp + wfpoff + (size_t)n0c * (ntp * 64));
    const float* bias = ((conv == 0) ? cb3 : (conv == 1) ? cb4 : cb5) + n0c;
    const int M = 126 - conv;

    int t = threadIdx.x;
    int w = t >> 6, lane = t & 63;
    int wm = w & 1, wn = w >> 1;
    int l15 = lane & 15, lhi = lane >> 4;

    // ---- issue A loads (linear dest) ----
    const char* wesrc = (const char*)(we_flat + (size_t)b * WE_STRIDE);
#pragma unroll
    for (int q = 0; q < 20; ++q) {
        int ci = (q << 8) + t;
        gld_lds16(wesrc + ((size_t)ci << 4), (char*)we_lds + (ci << 4));
    }
    const char* pssrc = (const char*)(posflat + (size_t)b * POS_STRIDE);
#pragma unroll
    for (int q = 0; q < 7; ++q) {
        int ci = (q << 8) + t;
        if (ci < 1664) gld_lds16(pssrc + ((size_t)ci << 4), (char*)pos_lds + (ci << 4));
    }

    // B staging: linear dest, source chunk pre-swizzled (involution)
#define STAGEB(BUF, T)                                                          \
    {                                                                           \
        int isw_ = (T) < ntw;                                                   \
        const char* base_ = isw_ ? Bw : Bp;                                     \
        size_t str_ = isw_ ? kwB : kpB;                                         \
        size_t kb_ = (size_t)(isw_ ? (T) : (T) - ntw) << 7;                     \
        _Pragma("unroll")                                                       \
        for (int u = 0; u < 4; ++u) {                                           \
            int ci = (u << 8) + t;                                              \
            int fr = ci >> 3, cin = ci & 7;                                     \
            int sc = cin ^ (fr & 7);                                            \
            gld_lds16(base_ + (size_t)fr * str_ + kb_ + ((size_t)sc << 4),      \
                      (char*)sB + ((BUF) << 14) + (ci << 4));                   \
        }                                                                       \
    }

    STAGEB(0, 0);

    // ---- corr on VALU (overlaps the in-flight A/B loads) ----
    {
        float we0[15];
#pragma unroll
        for (int j = 0; j < 15; ++j)
            we0[j] = bf2f(we_flat[(size_t)b * WE_STRIDE + lane + (j << 6)]);
        const ushort_t* cwb = corrw + (size_t)conv * (FN_ * KC) + (size_t)n0c * KC;
        for (int fi = 0; fi < 32; ++fi) {
            int f = (w << 5) + fi;
            const ushort_t* cr = cwb + (size_t)f * KC + lane;
            float s = 0.f;
#pragma unroll
            for (int j = 0; j < 15; ++j) s += we0[j] * bf2f(cr[j << 6]);
#pragma unroll
            for (int off = 32; off; off >>= 1) s += __shfl_xor(s, off);
            if (lane == 0) corr_lds[f] = s;
        }
    }

    // per-row A base pointers
    const ushort_t* weRow[4];
    const ushort_t* posRow[4];
#pragma unroll
    for (int mf = 0; mf < 4; ++mf) {
        int row = (wm << 6) + (mf << 4) + l15;
        weRow[mf]  = we_lds  + row * 300;
        posRow[mf] = pos_lds + row * 100;
    }

    f32x4 acc[4][4] = {};
    int cur = 0;
    for (int kt = 0; kt < nt; ++kt) {
        if (kt + 1 < nt) { STAGEB(cur ^ 1, kt + 1); WAITV4; }
        else WAITV0;
        BAR;

        int isw = kt < ntw;
        int kbase = (isw ? kt : kt - ntw) << 6;
        const ushort_t* cB = sB[cur];
#pragma unroll
        for (int ks = 0; ks < 2; ++ks) {
            int kk = kbase + (ks << 5) + (lhi << 3);
            bf16x8 afr[4], bfr[4];
#pragma unroll
            for (int mf = 0; mf < 4; ++mf)
                afr[mf] = lds_ld8((isw ? weRow[mf] : posRow[mf]) + kk);
#pragma unroll
            for (int nf = 0; nf < 4; ++nf) {
                int fr = (wn << 6) + (nf << 4) + l15;
                int pc = ((ks << 2) + lhi) ^ (fr & 7);
                bfr[nf] = *(const bf16x8*)&cB[fr * 64 + pc * 8];
            }
            __builtin_amdgcn_s_setprio(1);
#pragma unroll
            for (int mf = 0; mf < 4; ++mf)
#pragma unroll
                for (int nf = 0; nf < 4; ++nf)
                    acc[mf][nf] = __builtin_amdgcn_mfma_f32_16x16x32_bf16(
                        afr[mf], bfr[nf], acc[mf][nf], 0, 0, 0);
            __builtin_amdgcn_s_setprio(0);
        }
        BAR;
        cur ^= 1;
    }
#undef STAGEB

    // ---- epilogue: row-0 corr subtract, masked max, bias+tanh ----
#pragma unroll
    for (int nf = 0; nf < 4; ++nf) {
        int col = (wn << 6) + (nf << 4) + l15;
        float bmax = -INFINITY;
#pragma unroll
        for (int mf = 0; mf < 4; ++mf) {
#pragma unroll
            for (int j = 0; j < 4; ++j) {
                int i = (wm << 6) + (mf << 4) + (lhi << 2) + j;
                float v = acc[mf][nf][j];
                if (i == 0) v -= corr_lds[col];
                if (i < M) bmax = fmaxf(bmax, v);
            }
        }
        bmax = fmaxf(bmax, __shfl_xor(bmax, 16));
        bmax = fmaxf(bmax, __shfl_xor(bmax, 32));
        if (lane < 16) red[wm][col] = bmax;
    }
    __syncthreads();
    if (t < 128) {
        float m = fmaxf(red[0][t], red[1][t]);
        sf[(size_t)b * (3 * FN_) + (conv << 8) + n0c + t] = tanhf(m + bias[t]);
    }
}

// ---- tail: span/lex feats + g + final logits, one block per b ----
__device__ __forceinline__ int tok_at(const int* inputs, int b, int idx) {
    return (idx >= 0 && idx < L_) ? inputs[b * L_ + idx] : 0;
}
__global__ __launch_bounds__(256) void tail_kernel(
    const int* __restrict__ inputs,
    const int* __restrict__ e1s, const int* __restrict__ e1e,
    const int* __restrict__ e2s, const int* __restrict__ e2e,
    const float* __restrict__ emb, const float* __restrict__ sf,
    const float* __restrict__ W1, const float* __restrict__ b1,
    const float* __restrict__ W2, const float* __restrict__ b2,
    float* __restrict__ y)
{
    __shared__ float o_loc[1900];
    __shared__ float sfl[3 * FN_];

    int b = blockIdx.x, t = threadIdx.x;
    int lane = t & 63, w = t >> 6;

    for (int k = t; k < 3 * FN_; k += 256) sfl[k] = sf[(size_t)b * (3 * FN_) + k];

    int s1 = e1s[b], t1 = e1e[b], s2 = e2s[b], t2 = e2e[b];
    float inv1 = 1.f / (float)(t1 - s1 + 1);
    float inv2 = 1.f / (float)(t2 - s2 + 1);
    int ta = tok_at(inputs, b, s1 - 1), tb = tok_at(inputs, b, t1 + 1);
    int tc = tok_at(inputs, b, s2 - 1), td = tok_at(inputs, b, t2 + 1);
    for (int d = t; d < E_; d += 256) {
        float s = 0.f;
        for (int p = s1; p <= t1; ++p) s += emb[(size_t)tok_at(inputs, b, p) * E_ + d];
        o_loc[d] = s * inv1;
        s = 0.f;
        for (int p = s2; p <= t2; ++p) s += emb[(size_t)tok_at(inputs, b, p) * E_ + d];
        o_loc[E_ + d] = s * inv2;
        o_loc[2 * E_ + d] = emb[(size_t)ta * E_ + d];
        o_loc[3 * E_ + d] = emb[(size_t)tb * E_ + d];
        o_loc[4 * E_ + d] = emb[(size_t)tc * E_ + d];
        o_loc[5 * E_ + d] = emb[(size_t)td * E_ + d];
    }
    __syncthreads();

    for (int h = w; h < H2_; h += 4) {
        const float* wr = W1 + (size_t)h * (3 * FN_);
        float acc = 0.f;
#pragma unroll
        for (int j = 0; j < 12; ++j) acc += sfl[lane + (j << 6)] * wr[lane + (j << 6)];
        for (int off = 32; off; off >>= 1) acc += __shfl_down(acc, off);
        if (lane == 0) o_loc[1800 + h] = tanhf(acc + b1[h]);
    }
    __syncthreads();

    for (int lab = w; lab < LAB_; lab += 4) {
        const float* wr = W2 + (size_t)lab * 1900;
        float acc = 0.f;
        for (int d = lane; d < 1900; d += 64) acc += o_loc[d] * wr[d];
        for (int off = 32; off; off >>= 1) acc += __shfl_down(acc, off);
        if (lane == 0) y[(size_t)b * LAB_ + lab] = acc + b2[lab];
    }
}

extern "C" void kernel_launch(void* const* d_in, const int* in_sizes, int n_in,
                              void* d_out, int out_size, void* d_ws, size_t ws_size,
                              hipStream_t stream) {
    const int*   inputs = (const int*)d_in[0];
    const int*   e1s    = (const int*)d_in[1];
    const int*   e1e    = (const int*)d_in[2];
    const int*   e2s    = (const int*)d_in[3];
    const int*   e2e    = (const int*)d_in[4];
    const int*   p1     = (const int*)d_in[5];
    const int*   p2     = (const int*)d_in[6];
    const float* emb    = (const float*)d_in[7];
    const float* pos1   = (const float*)d_in[8];
    const float* pos2   = (const float*)d_in[9];
    const float* w3     = (const float*)d_in[10];
    const float* cb3    = (const float*)d_in[11];
    const float* w4     = (const float*)d_in[12];
    const float* cb4    = (const float*)d_in[13];
    const float* w5     = (const float*)d_in[14];
    const float* cb5    = (const float*)d_in[15];
    const float* W1     = (const float*)d_in[16];
    const float* b1     = (const float*)d_in[17];
    const float* W2     = (const float*)d_in[18];
    const float* b2     = (const float*)d_in[19];
    float* y = (float*)d_out;

    char* ws = (char*)d_ws;
    size_t off = 0;
    ushort_t* we_flat = (ushort_t*)(ws + off); off += (size_t)N_WE * 2;
    ushort_t* posflat = (ushort_t*)(ws + off); off += (size_t)N_POS * 2;
    ushort_t* wfw     = (ushort_t*)(ws + off); off += (size_t)N_WFW * 2;
    ushort_t* wfp     = (ushort_t*)(ws + off); off += (size_t)N_WFP * 2;
    ushort_t* corrw   = (ushort_t*)(ws + off); off += (size_t)N_CORR * 2;
    float*    sf      = (float*)(ws + off);    off += (size_t)B_ * 3 * FN_ * 4;

    setup_kernel<<<dim3(SETUP_BLOCKS), dim3(256), 0, stream>>>(
        inputs, p1, p2, emb, pos1, pos2, w3, w4, w5,
        we_flat, posflat, wfw, wfp, corrw);

    conv_fold<<<dim3(B_, 6), dim3(256), 0, stream>>>(
        we_flat, posflat, wfw, wfp, corrw, cb3, cb4, cb5, sf);

    tail_kernel<<<dim3(B_), dim3(256), 0, stream>>>(
        inputs, e1s, e1e, e2s, e2e, emb, sf, W1, b1, W2, b2, y);
}

// Round 9
// 188.181 us; speedup vs baseline: 1.3109x; 1.3109x over previous
//
#include <hip/hip_runtime.h>
#include <math.h>

#define B_   128
#define L_   128
#define E_   300
#define P_   50
#define FN_  256
#define H2_  100
#define LAB_ 19

typedef unsigned short ushort_t;
typedef __attribute__((ext_vector_type(8))) short bf16x8;
typedef __attribute__((ext_vector_type(4))) short bf16x4;
typedef __attribute__((ext_vector_type(4))) short short4v;
typedef __attribute__((ext_vector_type(4))) float f32x4;

// folded-K geometry: word K=(k+2)*300 pad64, pos K=k*100 pad64, corr K=960
#define KW0 1536
#define KW1 1856
#define KW2 2112
#define KP0 320
#define KP1 448
#define KP2 512
#define KC  960

#define WE_STRIDE  40960   // per-b we_flat elems (130x300 + zero tail)
#define POS_STRIDE 13312   // per-b posflat elems (128x100 + zero tail)

#define N_WE   (B_ * WE_STRIDE)
#define N_POS  (B_ * POS_STRIDE)
#define N_WFW  (FN_ * (KW0 + KW1 + KW2))
#define N_WFP  (FN_ * (KP0 + KP1 + KP2))
#define N_CORR (3 * FN_ * KC)

#define WEB  (B_ * 35)
#define POSB (B_ * 17)
#define WFWB (N_WFW / 2048)
#define WFPB (N_WFP / 2048)
#define CORB (N_CORR / 2048)
#define SETUP_BLOCKS (WEB + POSB + WFWB + WFPB + CORB)

__device__ __forceinline__ ushort_t f2bf(float x) {
    unsigned u = __float_as_uint(x);
    u += 0x7FFFu + ((u >> 16) & 1u);
    return (ushort_t)(u >> 16);
}
__device__ __forceinline__ float bf2f(ushort_t u) {
    return __uint_as_float((unsigned)u << 16);
}

__device__ __forceinline__ void gld_lds16(const void* g, void* lds_uniform) {
    __builtin_amdgcn_global_load_lds(
        (const __attribute__((address_space(1))) void*)g,
        (__attribute__((address_space(3))) void*)lds_uniform,
        16, 0, 0);
}

// 8 bf16 via two 8B loads (source only guaranteed 8B-aligned: row strides 600/200B)
__device__ __forceinline__ bf16x8 ld8_pair(const ushort_t* p) {
    bf16x4 lo = *(const bf16x4*)p;
    bf16x4 hi = *(const bf16x4*)(p + 4);
    return __builtin_shufflevector(lo, hi, 0, 1, 2, 3, 4, 5, 6, 7);
}

#define MEMFENCE asm volatile("" ::: "memory")
#define BAR      do { MEMFENCE; __builtin_amdgcn_s_barrier(); MEMFENCE; } while (0)
#define WAITV4   asm volatile("s_waitcnt vmcnt(4)" ::: "memory")
#define WAITV0   asm volatile("s_waitcnt vmcnt(0)" ::: "memory")

// ================= setup: vectorized x8 builds of all staging arrays =========
__global__ __launch_bounds__(256) void setup_kernel(
    const int* __restrict__ inputs, const int* __restrict__ p1, const int* __restrict__ p2,
    const float* __restrict__ emb, const float* __restrict__ pos1, const float* __restrict__ pos2,
    const float* __restrict__ w3, const float* __restrict__ w4, const float* __restrict__ w5,
    ushort_t* __restrict__ we_flat, ushort_t* __restrict__ posflat,
    ushort_t* __restrict__ wfw, ushort_t* __restrict__ wfp, ushort_t* __restrict__ corrw)
{
    int bid = blockIdx.x, t = threadIdx.x;

    if (bid < WEB) {                                  // ---- we_flat
        int b = bid / 35, rb = bid - b * 35;
        int r = rb * 4 + (t >> 6), c8 = t & 63;
        if (c8 >= 38) return;
        int e0 = c8 * 8;
        int n = (e0 + 8 <= 300) ? 8 : 300 - e0;       // 4 at c8=37
        int flat = r * 300 + e0;
        ushort_t* dst = we_flat + (size_t)b * WE_STRIDE + flat;
        if (r < 130) {
            int tok = (r == 0 || r == 129) ? 0 : inputs[b * L_ + r - 1];
            const float* er = emb + (size_t)tok * 300 + e0;
            short4v v0, v1;
#pragma unroll
            for (int m = 0; m < 4; ++m) v0[m] = (short)f2bf(er[m]);
            *(short4v*)dst = v0;
            if (n == 8) {
#pragma unroll
                for (int m = 0; m < 4; ++m) v1[m] = (short)f2bf(er[4 + m]);
                *(short4v*)(dst + 4) = v1;
            }
        } else {                                      // zero tail rows
            short4v z = {0, 0, 0, 0};
            if (flat + 4 <= WE_STRIDE) *(short4v*)dst = z;
            if (n == 8 && flat + 8 <= WE_STRIDE) *(short4v*)(dst + 4) = z;
        }
        return;
    }
    bid -= WEB;
    if (bid < POSB) {                                 // ---- posflat
        int b = bid / 17, rb = bid - b * 17;
        int r = rb * 8 + (t >> 5), c = t & 31;
        if (c >= 25) return;
        int e0 = c * 4;
        int flat = r * 100 + e0;
        ushort_t* dst = posflat + (size_t)b * POS_STRIDE + flat;
        short4v v;
        if (r < 128) {
            int pp1 = p1[b * L_ + r], pp2 = p2[b * L_ + r];
#pragma unroll
            for (int m = 0; m < 4; ++m) {
                int d = e0 + m;
                float x = (d < 50) ? pos1[(size_t)pp1 * 50 + d]
                                   : pos2[(size_t)pp2 * 50 + (d - 50)];
                v[m] = (short)f2bf(x);
            }
            *(short4v*)dst = v;
        } else {
            short4v z = {0, 0, 0, 0};
            if (flat + 4 <= POS_STRIDE) *(short4v*)dst = z;
        }
        return;
    }
    bid -= POSB;
    if (bid < WFWB) {                                 // ---- folded word weights
        int e = (bid * 256 + t) * 8;
        int conv, k;
        const float* w;
        int seg = e;
        if (seg < FN_ * KW0)                { conv = 0; k = 3; w = w3; }
        else if ((seg -= FN_ * KW0) < FN_ * KW1) { conv = 1; k = 4; w = w4; }
        else                                { seg -= FN_ * KW1; conv = 2; k = 5; w = w5; }
        int f, kk0;
        if (conv == 0) { f = seg / KW0; kk0 = seg - f * KW0; }
        else if (conv == 1) { f = seg / KW1; kk0 = seg - f * KW1; }
        else { f = seg / KW2; kk0 = seg - f * KW2; }
        bf16x8 v;
#pragma unroll
        for (int m = 0; m < 8; ++m) {
            int kk = kk0 + m;
            float s = 0.f;
            if (kk < (k + 2) * 300) {
                int mr = kk / 300, c = kk - mr * 300;
                int jlo = (mr - 2 < 0) ? 0 : mr - 2;
                int jhi = (mr < k - 1) ? mr : k - 1;
                for (int j = jlo; j <= jhi; ++j)
                    s += w[(size_t)f * (k * 1000) + j * 1000 + (mr - j) * 300 + c];
            }
            v[m] = (short)f2bf(s);
        }
        *(bf16x8*)(wfw + e) = v;
        return;
    }
    bid -= WFWB;
    if (bid < WFPB) {                                 // ---- pos weights
        int e = (bid * 256 + t) * 8;
        int conv, k;
        const float* w;
        int seg = e;
        if (seg < FN_ * KP0)                { conv = 0; k = 3; w = w3; }
        else if ((seg -= FN_ * KP0) < FN_ * KP1) { conv = 1; k = 4; w = w4; }
        else                                { seg -= FN_ * KP1; conv = 2; k = 5; w = w5; }
        int f, kk0;
        if (conv == 0) { f = seg / KP0; kk0 = seg - f * KP0; }
        else if (conv == 1) { f = seg / KP1; kk0 = seg - f * KP1; }
        else { f = seg / KP2; kk0 = seg - f * KP2; }
        bf16x8 v;
#pragma unroll
        for (int m = 0; m < 8; ++m) {
            int kk = kk0 + m;
            float x = 0.f;
            if (kk < k * 100) {
                int j = kk / 100, c = kk - j * 100;
                x = w[(size_t)f * (k * 1000) + j * 1000 + 900 + c];
            }
            v[m] = (short)f2bf(x);
        }
        *(bf16x8*)(wfp + e) = v;
        return;
    }
    bid -= WFPB;
    {                                                 // ---- corr weights w[f,0,0:900]
        int e = (bid * 256 + t) * 8;
        int conv = e / (FN_ * KC), seg = e - conv * (FN_ * KC);
        int k = 3 + conv;
        const float* w = (conv == 0) ? w3 : (conv == 1) ? w4 : w5;
        int f = seg / KC, kk0 = seg - f * KC;
        bf16x8 v;
#pragma unroll
        for (int m = 0; m < 8; ++m) {
            int kk = kk0 + m;
            v[m] = (kk < 900) ? (short)f2bf(w[(size_t)f * (k * 1000) + kk]) : (short)0;
        }
        *(bf16x8*)(corrw + e) = v;
    }
}

// ===== conv: grid (b, conv, nhalf); A-frags DIRECT FROM GLOBAL (L1/L2-hot),
// only B in LDS (dbuf 32 KB, swizzled) -> 3-4 blocks/CU, 12-16 waves.
// 4 waves 2m x 2n, wave tile 64x64 (acc 4x4). Corr on VALU. Counted vmcnt.
__global__ __launch_bounds__(256, 3) void conv_fold(
    const ushort_t* __restrict__ we_flat, const ushort_t* __restrict__ posflat,
    const ushort_t* __restrict__ wfw, const ushort_t* __restrict__ wfp,
    const ushort_t* __restrict__ corrw,
    const float* __restrict__ cb3, const float* __restrict__ cb4, const float* __restrict__ cb5,
    float* __restrict__ sf)
{
    __shared__ ushort_t sB[2][8192];          // 2 x 16 KB (chunk-swizzled)
    __shared__ float corr_lds[128];
    __shared__ float red[2][128];

    int b    = blockIdx.x;
    int conv = blockIdx.y;
    int n0c  = blockIdx.z << 7;

    const int ntw = (conv == 0) ? KW0 / 64 : (conv == 1) ? KW1 / 64 : KW2 / 64;
    const int ntp = (conv == 0) ? KP0 / 64 : (conv == 1) ? KP1 / 64 : KP2 / 64;
    const int nt  = ntw + ntp;
    const size_t kwB = (size_t)(ntw * 64) * 2;     // B row stride, bytes
    const size_t kpB = (size_t)(ntp * 64) * 2;
    const size_t wfwoff = (conv == 0) ? 0 : (conv == 1) ? (size_t)FN_ * KW0 : (size_t)FN_ * (KW0 + KW1);
    const size_t wfpoff = (conv == 0) ? 0 : (conv == 1) ? (size_t)FN_ * KP0 : (size_t)FN_ * (KP0 + KP1);
    const char* Bw = (const char*)(wfw + wfwoff + (size_t)n0c * (ntw * 64));
    const char* Bp = (const char*)(wfp + wfpoff + (size_t)n0c * (ntp * 64));
    const float* bias = ((conv == 0) ? cb3 : (conv == 1) ? cb4 : cb5) + n0c;
    const int M = 126 - conv;

    int t = threadIdx.x;
    int w = t >> 6, lane = t & 63;
    int wm = w & 1, wn = w >> 1;
    int l15 = lane & 15, lhi = lane >> 4;

#define STAGEB(BUF, T)                                                          \
    {                                                                           \
        int isw_ = (T) < ntw;                                                   \
        const char* base_ = isw_ ? Bw : Bp;                                     \
        size_t str_ = isw_ ? kwB : kpB;                                         \
        size_t kb_ = (size_t)(isw_ ? (T) : (T) - ntw) << 7;                     \
        _Pragma("unroll")                                                       \
        for (int u = 0; u < 4; ++u) {                                           \
            int ci = (u << 8) + t;                                              \
            int fr = ci >> 3, cin = ci & 7;                                     \
            int sc = cin ^ (fr & 7);                                            \
            gld_lds16(base_ + (size_t)fr * str_ + kb_ + ((size_t)sc << 4),      \
                      (char*)sB + ((BUF) << 14) + (ci << 4));                   \
        }                                                                       \
    }

    STAGEB(0, 0);

    // ---- corr on VALU (overlaps the in-flight B staging) ----
    {
        float we0[15];
#pragma unroll
        for (int j = 0; j < 15; ++j)
            we0[j] = bf2f(we_flat[(size_t)b * WE_STRIDE + lane + (j << 6)]);
        const ushort_t* cwb = corrw + (size_t)conv * (FN_ * KC) + (size_t)n0c * KC;
        for (int fi = 0; fi < 32; ++fi) {
            int f = (w << 5) + fi;
            const ushort_t* cr = cwb + (size_t)f * KC + lane;
            float s = 0.f;
#pragma unroll
            for (int j = 0; j < 15; ++j) s += we0[j] * bf2f(cr[j << 6]);
#pragma unroll
            for (int off = 32; off; off >>= 1) s += __shfl_xor(s, off);
            if (lane == 0) corr_lds[f] = s;
        }
    }

    // per-mf A row base pointers (global)
    const ushort_t* rowW[4];
    const ushort_t* rowP[4];
#pragma unroll
    for (int mf = 0; mf < 4; ++mf) {
        int row = (wm << 6) + (mf << 4) + l15;
        rowW[mf] = we_flat + (size_t)b * WE_STRIDE  + row * 300;
        rowP[mf] = posflat + (size_t)b * POS_STRIDE + row * 100;
    }

    f32x4 acc[4][4] = {};
    int cur = 0;
    for (int kt = 0; kt < nt; ++kt) {
        if (kt + 1 < nt) { STAGEB(cur ^ 1, kt + 1); WAITV4; }
        else WAITV0;
        BAR;

        int isw = kt < ntw;
        int kbase = (isw ? kt : kt - ntw) << 6;

        // preload all 8 A-frags for this K64 tile (global, L1/L2-hot)
        bf16x8 afr[2][4];
#pragma unroll
        for (int ks = 0; ks < 2; ++ks) {
            int kk = kbase + (ks << 5) + (lhi << 3);
#pragma unroll
            for (int mf = 0; mf < 4; ++mf)
                afr[ks][mf] = ld8_pair((isw ? rowW[mf] : rowP[mf]) + kk);
        }

        const ushort_t* cB = sB[cur];
#pragma unroll
        for (int ks = 0; ks < 2; ++ks) {
            bf16x8 bfr[4];
#pragma unroll
            for (int nf = 0; nf < 4; ++nf) {
                int fr = (wn << 6) + (nf << 4) + l15;
                int pc = ((ks << 2) + lhi) ^ (fr & 7);
                bfr[nf] = *(const bf16x8*)&cB[fr * 64 + pc * 8];
            }
            __builtin_amdgcn_s_setprio(1);
#pragma unroll
            for (int mf = 0; mf < 4; ++mf)
#pragma unroll
                for (int nf = 0; nf < 4; ++nf)
                    acc[mf][nf] = __builtin_amdgcn_mfma_f32_16x16x32_bf16(
                        afr[ks][mf], bfr[nf], acc[mf][nf], 0, 0, 0);
            __builtin_amdgcn_s_setprio(0);
        }
        BAR;
        cur ^= 1;
    }
#undef STAGEB

    // ---- epilogue: row-0 corr subtract, masked max, bias+tanh ----
#pragma unroll
    for (int nf = 0; nf < 4; ++nf) {
        int col = (wn << 6) + (nf << 4) + l15;
        float bmax = -INFINITY;
#pragma unroll
        for (int mf = 0; mf < 4; ++mf) {
#pragma unroll
            for (int j = 0; j < 4; ++j) {
                int i = (wm << 6) + (mf << 4) + (lhi << 2) + j;
                float v = acc[mf][nf][j];
                if (i == 0) v -= corr_lds[col];
                if (i < M) bmax = fmaxf(bmax, v);
            }
        }
        bmax = fmaxf(bmax, __shfl_xor(bmax, 16));
        bmax = fmaxf(bmax, __shfl_xor(bmax, 32));
        if (lane < 16) red[wm][col] = bmax;
    }
    __syncthreads();
    if (t < 128) {
        float m = fmaxf(red[0][t], red[1][t]);
        sf[(size_t)b * (3 * FN_) + (conv << 8) + n0c + t] = tanhf(m + bias[t]);
    }
}

// ---- tail: span/lex feats + g + final logits, one block per b ----
__device__ __forceinline__ int tok_at(const int* inputs, int b, int idx) {
    return (idx >= 0 && idx < L_) ? inputs[b * L_ + idx] : 0;
}
__global__ __launch_bounds__(256) void tail_kernel(
    const int* __restrict__ inputs,
    const int* __restrict__ e1s, const int* __restrict__ e1e,
    const int* __restrict__ e2s, const int* __restrict__ e2e,
    const float* __restrict__ emb, const float* __restrict__ sf,
    const float* __restrict__ W1, const float* __restrict__ b1,
    const float* __restrict__ W2, const float* __restrict__ b2,
    float* __restrict__ y)
{
    __shared__ float o_loc[1900];
    __shared__ float sfl[3 * FN_];

    int b = blockIdx.x, t = threadIdx.x;
    int lane = t & 63, w = t >> 6;

    for (int k = t; k < 3 * FN_; k += 256) sfl[k] = sf[(size_t)b * (3 * FN_) + k];

    int s1 = e1s[b], t1 = e1e[b], s2 = e2s[b], t2 = e2e[b];
    float inv1 = 1.f / (float)(t1 - s1 + 1);
    float inv2 = 1.f / (float)(t2 - s2 + 1);
    int ta = tok_at(inputs, b, s1 - 1), tb = tok_at(inputs, b, t1 + 1);
    int tc = tok_at(inputs, b, s2 - 1), td = tok_at(inputs, b, t2 + 1);
    for (int d = t; d < E_; d += 256) {
        float s = 0.f;
        for (int p = s1; p <= t1; ++p) s += emb[(size_t)tok_at(inputs, b, p) * E_ + d];
        o_loc[d] = s * inv1;
        s = 0.f;
        for (int p = s2; p <= t2; ++p) s += emb[(size_t)tok_at(inputs, b, p) * E_ + d];
        o_loc[E_ + d] = s * inv2;
        o_loc[2 * E_ + d] = emb[(size_t)ta * E_ + d];
        o_loc[3 * E_ + d] = emb[(size_t)tb * E_ + d];
        o_loc[4 * E_ + d] = emb[(size_t)tc * E_ + d];
        o_loc[5 * E_ + d] = emb[(size_t)td * E_ + d];
    }
    __syncthreads();

    for (int h = w; h < H2_; h += 4) {
        const float* wr = W1 + (size_t)h * (3 * FN_);
        float acc = 0.f;
#pragma unroll
        for (int j = 0; j < 12; ++j) acc += sfl[lane + (j << 6)] * wr[lane + (j << 6)];
        for (int off = 32; off; off >>= 1) acc += __shfl_down(acc, off);
        if (lane == 0) o_loc[1800 + h] = tanhf(acc + b1[h]);
    }
    __syncthreads();

    for (int lab = w; lab < LAB_; lab += 4) {
        const float* wr = W2 + (size_t)lab * 1900;
        float acc = 0.f;
        for (int d = lane; d < 1900; d += 64) acc += o_loc[d] * wr[d];
        for (int off = 32; off; off >>= 1) acc += __shfl_down(acc, off);
        if (lane == 0) y[(size_t)b * LAB_ + lab] = acc + b2[lab];
    }
}

extern "C" void kernel_launch(void* const* d_in, const int* in_sizes, int n_in,
                              void* d_out, int out_size, void* d_ws, size_t ws_size,
                              hipStream_t stream) {
    const int*   inputs = (const int*)d_in[0];
    const int*   e1s    = (const int*)d_in[1];
    const int*   e1e    = (const int*)d_in[2];
    const int*   e2s    = (const int*)d_in[3];
    const int*   e2e    = (const int*)d_in[4];
    const int*   p1     = (const int*)d_in[5];
    const int*   p2     = (const int*)d_in[6];
    const float* emb    = (const float*)d_in[7];
    const float* pos1   = (const float*)d_in[8];
    const float* pos2   = (const float*)d_in[9];
    const float* w3     = (const float*)d_in[10];
    const float* cb3    = (const float*)d_in[11];
    const float* w4     = (const float*)d_in[12];
    const float* cb4    = (const float*)d_in[13];
    const float* w5     = (const float*)d_in[14];
    const float* cb5    = (const float*)d_in[15];
    const float* W1     = (const float*)d_in[16];
    const float* b1     = (const float*)d_in[17];
    const float* W2     = (const float*)d_in[18];
    const float* b2     = (const float*)d_in[19];
    float* y = (float*)d_out;

    char* ws = (char*)d_ws;
    size_t off = 0;
    ushort_t* we_flat = (ushort_t*)(ws + off); off += (size_t)N_WE * 2;
    ushort_t* posflat = (ushort_t*)(ws + off); off += (size_t)N_POS * 2;
    ushort_t* wfw     = (ushort_t*)(ws + off); off += (size_t)N_WFW * 2;
    ushort_t* wfp     = (ushort_t*)(ws + off); off += (size_t)N_WFP * 2;
    ushort_t* corrw   = (ushort_t*)(ws + off); off += (size_t)N_CORR * 2;
    float*    sf      = (float*)(ws + off);    off += (size_t)B_ * 3 * FN_ * 4;

    setup_kernel<<<dim3(SETUP_BLOCKS), dim3(256), 0, stream>>>(
        inputs, p1, p2, emb, pos1, pos2, w3, w4, w5,
        we_flat, posflat, wfw, wfp, corrw);

    conv_fold<<<dim3(B_, 3, 2), dim3(256), 0, stream>>>(
        we_flat, posflat, wfw, wfp, corrw, cb3, cb4, cb5, sf);

    tail_kernel<<<dim3(B_), dim3(256), 0, stream>>>(
        inputs, e1s, e1e, e2s, e2e, emb, sf, W1, b1, W2, b2, y);
}